// Round 10
// baseline (433.222 us; speedup 1.0000x reference)
//
#include <hip/hip_runtime.h>

// Problem constants (from reference)
#define CC 9605
#define BB 2048
#define LL 8
#define CAND_MAX 384     // fallback candidate cap
#define ROWCAP 96        // per-row collected-candidate cap
#define NEGF (-1e30f)

// d_ws layout:
//   wsu[0] = wl entry count (atomic)   wsu[1] = dtype sniff flags
//   wsu[3] = tau (enc threshold, written by pick_tau16)
//   wsu[4 .. 4+2048)   whitelist entries (col<<8 | mask)
//   byte 16384: float partials[2048]
//   byte 24576: unsigned counts[2048]
//   byte 32768: unsigned cand[2048*96]  (~786 KB)
//   NOTE: hist16 (65536 bins, 256 KB) ALSO lives at byte 32768 — it is
//   consumed by pick_tau16 BEFORE stream_collect overwrites with cand.
#define WS_PARTIALS_OFF 16384
#define WS_COUNTS_OFF 24576
#define WS_CAND_OFF 32768

__device__ __forceinline__ unsigned enc_f(float f) {
  unsigned u = __float_as_uint(f);
  return (u & 0x80000000u) ? ~u : (u | 0x80000000u);
}
__device__ __forceinline__ float dec_u(unsigned e) {
  unsigned u = (e & 0x80000000u) ? (e & 0x7fffffffu) : ~e;
  return __uint_as_float(u);
}
__device__ __forceinline__ float sigm(float z) {
  return 1.0f / (1.0f + __expf(-z));
}

// ---- dtype sniff: byte signatures over the raw wl buffer ----
__global__ void wl_sniff(const unsigned* __restrict__ wlw,
                         unsigned* __restrict__ wsu) {
  const int nwords = (LL * CC) / 4;
  const int stride = gridDim.x * blockDim.x;
  unsigned f = 0u;
  for (int j = blockIdx.x * blockDim.x + threadIdx.x; j < nwords; j += stride) {
    unsigned w = wlw[j];
#pragma unroll
    for (int k = 0; k < 4; ++k) {
      unsigned b = (w >> (8 * k)) & 255u;
      if (b == 1u)    { f |= 2u; if (k != 0) f |= 1u; }
      if (b == 0x3fu) { f |= 8u; if (k == 1) f |= 4u; }
    }
  }
#pragma unroll
  for (int off = 32; off >= 1; off >>= 1) f |= __shfl_xor(f, off, 64);
  if ((threadIdx.x & 63) == 0 && f) atomicOr(&wsu[1], f);
}

__global__ void wl_compact(const unsigned char* __restrict__ wl,
                           unsigned* __restrict__ wsu) {
  const int tid = threadIdx.x;
  const int lane = tid & 63;
  const int c = blockIdx.x * 256 + tid;
  const unsigned g = wsu[1];
  const int dt = (g & 1u) ? 0 : (g & 4u) ? 3 : (g & 2u) ? 1 : (g & 8u) ? 2 : 0;
  const int* wl32 = (const int*)wl;
  const float* wlf = (const float*)wl;
  const unsigned short* wlh = (const unsigned short*)wl;
  unsigned m = 0u;
  if (c < CC) {
#pragma unroll
    for (int l = 0; l < LL; ++l) {
      int j = l * CC + c;
      bool on;
      if (dt == 0) on = (wl[j] != 0);
      else if (dt == 1) on = (wl32[j] != 0);
      else if (dt == 2) on = (wlf[j] != 0.0f);
      else on = (wlh[j] != 0);
      if (on) m |= (1u << l);
    }
  }
  unsigned long long bal = __ballot(m != 0u);
  if (bal) {
    unsigned wcnt = (unsigned)__popcll(bal);
    unsigned basep = 0u;
    if (lane == 0) basep = atomicAdd(&wsu[0], wcnt);
    basep = __shfl(basep, 0, 64);
    if (m) {
      unsigned pos = basep + (unsigned)__popcll(bal & ((1ull << lane) - 1ull));
      if (pos < 2048u) wsu[4 + pos] = ((unsigned)c << 8) | m;
    }
  }
}

// ---- hist16: parallel coalesced sample -> 65536-bin histogram (enc>>16) ----
__global__ __launch_bounds__(256) void hist16(const float* __restrict__ x,
                                              unsigned* __restrict__ hist) {
  const int tid = threadIdx.x;
  const float4* xv = (const float4*)x;
  const int base = blockIdx.x * 19210;  // NG/256; chunks tile the full array
#pragma unroll
  for (int i = 0; i < 2; ++i) {
    float4 v = xv[base + (i << 8) + tid];
    atomicAdd(&hist[enc_f(v.x) >> 16], 1u);
    atomicAdd(&hist[enc_f(v.y) >> 16], 1u);
    atomicAdd(&hist[enc_f(v.z) >> 16], 1u);
    atomicAdd(&hist[enc_f(v.w) >> 16], 1u);
  }
}

// ---- pick_tau16: suffix-scan the 64K-bin histogram, pick tau ----
// RANK = 61440 (30/row target) * (524288 sample / 19671040 total) = 1637
__global__ __launch_bounds__(1024) void pick_tau16(
    const unsigned* __restrict__ hist, unsigned* __restrict__ wsu) {
  __shared__ unsigned suf[1024];
  __shared__ unsigned sChunk, sRank2;
  const int tid = threadIdx.x;
  unsigned s = 0u;
  const int b0 = tid << 6;
#pragma unroll
  for (int i = 0; i < 64; ++i) s += hist[b0 + i];
  suf[tid] = s;
  __syncthreads();
  for (int d = 1; d < 1024; d <<= 1) {
    unsigned add = (tid + d < 1024) ? suf[tid + d] : 0u;
    __syncthreads();
    suf[tid] += add;
    __syncthreads();
  }
  const unsigned RANK = 1637u;
  if (suf[tid] >= RANK && (tid == 1023 || suf[tid + 1] < RANK)) {
    sChunk = (unsigned)tid;
    sRank2 = RANK - ((tid == 1023) ? 0u : suf[tid + 1]);
  }
  __syncthreads();
  if (tid == 0) {
    unsigned chunk = sChunk, r = sRank2;
    unsigned acc = 0u;
    unsigned bin = chunk << 6;
    for (int i = 63; i >= 0; --i) {
      acc += hist[(chunk << 6) + (unsigned)i];
      if (acc >= r) { bin = (chunk << 6) + (unsigned)i; break; }
    }
    wsu[3] = bin << 16;
  }
}

// ---- stream_collect: pure coalesced stream of x; append enc>=tau per row ---
__global__ __launch_bounds__(256) void stream_collect(
    const float* __restrict__ x, const unsigned* __restrict__ wsu,
    unsigned* __restrict__ counts, unsigned* __restrict__ cand) {
  const unsigned tau = wsu[3];
  const int NG = (CC * BB) / 4;  // 4,917,760 exactly
  const int stride = gridDim.x * blockDim.x;
  const float4* xv = (const float4*)x;
  for (int g = blockIdx.x * blockDim.x + threadIdx.x; g < NG; g += stride) {
    float4 v = xv[g];
    unsigned idx = (unsigned)g << 2;
    unsigned r = idx / 9605u;          // compiler magic-mul
    unsigned rem = idx - r * 9605u;
    unsigned e0 = enc_f(v.x), e1 = enc_f(v.y);
    unsigned e2 = enc_f(v.z), e3 = enc_f(v.w);
    if (e0 >= tau) {
      unsigned s = atomicAdd(&counts[r], 1u);
      if (s < (unsigned)ROWCAP) cand[r * ROWCAP + s] = e0;
    }
    if (e1 >= tau) {
      unsigned rk = r + (rem + 1u >= 9605u);
      unsigned s = atomicAdd(&counts[rk], 1u);
      if (s < (unsigned)ROWCAP) cand[rk * ROWCAP + s] = e1;
    }
    if (e2 >= tau) {
      unsigned rk = r + (rem + 2u >= 9605u);
      unsigned s = atomicAdd(&counts[rk], 1u);
      if (s < (unsigned)ROWCAP) cand[rk * ROWCAP + s] = e2;
    }
    if (e3 >= tau) {
      unsigned rk = r + (rem + 3u >= 9605u);
      unsigned s = atomicAdd(&counts[rk], 1u);
      if (s < (unsigned)ROWCAP) cand[rk * ROWCAP + s] = e3;
    }
  }
}

// ---- finalize: per-row top-11 (from candidates, exact fallback if needed)
//      + whitelist gather + epilogue ----
__global__ __launch_bounds__(256) void finalize(
    const float* __restrict__ x, const float* __restrict__ y,
    const unsigned* __restrict__ wsu, const unsigned* __restrict__ counts,
    const unsigned* __restrict__ cand, float* __restrict__ partials) {
  __shared__ unsigned sh_cand[CAND_MAX];
  __shared__ unsigned sh_redM[4];
  __shared__ unsigned sh_redC[4];
  __shared__ unsigned sh_cnt;
  __shared__ unsigned sh_e11;
  __shared__ float sh_wl[4][10];

  const int tid = threadIdx.x;
  const int lane = tid & 63;
  const int wid = tid >> 6;
  const int b = blockIdx.x;
  const long long base = (long long)b * CC;

  // whitelist gather loads first (latency overlaps selection)
  const unsigned nu = wsu[0];
  const unsigned* ents = wsu + 4;
  const bool h0 = (unsigned)tid < nu;
  const bool h1 = (unsigned)(tid + 256) < nu;
  unsigned ent0 = 0u, ent1 = 0u;
  float gx0 = NEGF, gy0 = 0.0f, gx1 = NEGF, gy1 = 0.0f;
  if (h0) ent0 = ents[tid];
  if (h1) ent1 = ents[tid + 256];
  if (h0) { gx0 = x[base + (ent0 >> 8)]; gy0 = y[base + (ent0 >> 8)]; }
  if (h1) { gx1 = x[base + (ent1 >> 8)]; gy1 = y[base + (ent1 >> 8)]; }

  const unsigned cnt = counts[b];
  unsigned E11 = 0u;
  if (cnt >= 11u && cnt <= (unsigned)ROWCAP) {
    // ---- fast path: exact top-11 of collected candidates (wave 0) ----
    if (wid == 0) {
      const unsigned* gc = cand + (unsigned)b * ROWCAP;
      unsigned a0 = ((unsigned)lane < cnt) ? gc[lane] : 0u;
      unsigned a1 = ((unsigned)(lane + 64) < cnt) ? gc[lane + 64] : 0u;
      unsigned ans = 0u;
      for (int r = 0; r < 11; ++r) {
        unsigned lmx = max(a0, a1);
        unsigned wm = lmx;
#pragma unroll
        for (int off = 32; off >= 1; off >>= 1)
          wm = max(wm, __shfl_xor(wm, off, 64));
        ans = wm;
        if (r < 10) {
          unsigned long long bal = __ballot(lmx == wm);
          int first = (int)__ffsll((long long)bal) - 1;
          if (lane == first) {
            if (a0 == wm) a0 = 0u; else a1 = 0u;
          }
        }
      }
      if (lane == 0) sh_e11 = ans;
    }
    __syncthreads();
    E11 = sh_e11;
  } else {
    // ---- exact fallback: re-scan this row from global (L3-resident) ----
    if (tid == 0) sh_cnt = 0u;
    unsigned mx = 0u;
    for (int i = tid; i < CC; i += 256) mx = max(mx, enc_f(x[base + i]));
#pragma unroll
    for (int off = 32; off >= 1; off >>= 1)
      mx = max(mx, __shfl_xor(mx, off, 64));
    if (lane == 0) sh_redM[wid] = mx;
    __syncthreads();
    const unsigned Emax =
        max(max(sh_redM[0], sh_redM[1]), max(sh_redM[2], sh_redM[3]));

    auto gcount = [&](unsigned T) -> unsigned {
      unsigned c2 = 0u;
      for (int i = tid; i < CC; i += 256) c2 += (enc_f(x[base + i]) >= T);
#pragma unroll
      for (int off = 32; off >= 1; off >>= 1) c2 += __shfl_xor(c2, off, 64);
      __syncthreads();
      if (lane == 0) sh_redC[wid] = c2;
      __syncthreads();
      return sh_redC[0] + sh_redC[1] + sh_redC[2] + sh_redC[3];
    };

    const unsigned STEP = 1u << 22;
    bool done = false;
    unsigned lo = (Emax > STEP) ? (Emax - STEP) : 1u;
    unsigned hi = Emax + 1u;
    unsigned c = gcount(lo);
    while (c < 11u && lo > 1u) {
      hi = lo;
      lo = (lo > STEP) ? (lo - STEP) : 1u;
      c = gcount(lo);
    }
    while (c > CAND_MAX) {
      if (hi - lo <= 1u) { E11 = lo; done = true; break; }
      unsigned mid = lo + ((hi - lo) >> 1);
      unsigned cm = gcount(mid);
      if (cm >= 11u) { lo = mid; c = cm; } else { hi = mid; }
    }
    if (!done) {
      for (int i = tid; i < CC; i += 256) {
        unsigned e = enc_f(x[base + i]);
        bool pr = (e >= lo);
        unsigned long long bal = __ballot(pr);
        if (bal) {
          unsigned wcnt = (unsigned)__popcll(bal);
          unsigned basep = 0u;
          if (lane == 0) basep = atomicAdd(&sh_cnt, wcnt);
          basep = __shfl(basep, 0, 64);
          if (pr) {
            unsigned posn =
                basep + (unsigned)__popcll(bal & ((1ull << lane) - 1ull));
            sh_cand[posn] = e;
          }
        }
      }
      __syncthreads();
      if (wid == 0) {
        unsigned v0[6];
#pragma unroll
        for (int j = 0; j < 6; ++j) {
          unsigned idx = (unsigned)lane + 64u * j;
          v0[j] = (idx < c) ? sh_cand[idx] : 0u;
        }
        unsigned ans = 0u;
        for (int r = 0; r < 11; ++r) {
          unsigned lmx = v0[0];
#pragma unroll
          for (int j = 1; j < 6; ++j) lmx = max(lmx, v0[j]);
          unsigned wm = lmx;
#pragma unroll
          for (int off = 32; off >= 1; off >>= 1)
            wm = max(wm, __shfl_xor(wm, off, 64));
          ans = wm;
          if (r < 10) {
            unsigned long long bal = __ballot(lmx == wm);
            int first = (int)__ffsll((long long)bal) - 1;
            if (lane == first) {
              bool rm = false;
#pragma unroll
              for (int j = 0; j < 6; ++j)
                if (!rm && v0[j] == wm) { v0[j] = 0u; rm = true; }
            }
          }
        }
        if (lane == 0) sh_e11 = ans;
      }
      __syncthreads();
      E11 = sh_e11;
    }
  }

  // ---- whitelist gather reduce ----
  float lm[8];
#pragma unroll
  for (int l = 0; l < 8; ++l) lm[l] = NEGF;
  unsigned pmask = 0u;  // bits0-7: present; bits8-15: has positive
  if (h0) {
    unsigned mk = ent0 & 255u;
    pmask |= mk;
    if (gy0 > 0.0f) pmask |= (mk << 8);
#pragma unroll
    for (int l = 0; l < 8; ++l)
      if ((mk >> l) & 1u) lm[l] = fmaxf(lm[l], gx0);
  }
  if (h1) {
    unsigned mk = ent1 & 255u;
    pmask |= mk;
    if (gy1 > 0.0f) pmask |= (mk << 8);
#pragma unroll
    for (int l = 0; l < 8; ++l)
      if ((mk >> l) & 1u) lm[l] = fmaxf(lm[l], gx1);
  }
  for (unsigned e = (unsigned)tid + 512u; e < nu; e += 256u) {  // safety net
    unsigned ent = ents[e];
    unsigned mk = ent & 255u;
    float xv = x[base + (ent >> 8)];
    float yv = y[base + (ent >> 8)];
    pmask |= mk;
    if (yv > 0.0f) pmask |= (mk << 8);
#pragma unroll
    for (int l = 0; l < 8; ++l)
      if ((mk >> l) & 1u) lm[l] = fmaxf(lm[l], xv);
  }
#pragma unroll
  for (int off = 32; off >= 1; off >>= 1) {
    pmask |= __shfl_xor(pmask, off, 64);
#pragma unroll
    for (int l = 0; l < 8; ++l) lm[l] = fmaxf(lm[l], __shfl_xor(lm[l], off, 64));
  }
  if (lane == 0) {
#pragma unroll
    for (int l = 0; l < 8; ++l) sh_wl[wid][l] = lm[l];
    sh_wl[wid][8] = __uint_as_float(pmask);
  }
  __syncthreads();

  // ---- epilogue ----
  if (tid == 0) {
    float LM[8];
    unsigned PM = 0u;
#pragma unroll
    for (int l = 0; l < 8; ++l) LM[l] = NEGF;
    for (int w = 0; w < 4; ++w) {
#pragma unroll
      for (int l = 0; l < 8; ++l) LM[l] = fmaxf(LM[l], sh_wl[w][l]);
      PM |= __float_as_uint(sh_wl[w][8]);
    }
    unsigned PR = PM & 255u, PO = (PM >> 8) & 255u;
    float thres = fmaxf(sigm(dec_u(E11)), 0.5f);
    float cmax = NEGF, imax = NEGF, umax = NEGF;
#pragma unroll
    for (int l = 0; l < 8; ++l) {
      if ((PR >> l) & 1u) {
        float ml = sigm(LM[l]);
        umax = fmaxf(umax, ml);
        if ((PO >> l) & 1u) cmax = fmaxf(cmax, ml);
        else imax = fmaxf(imax, ml);
      }
    }
    bool anyc = (PO != 0u);
    bool anyi = (PO != 255u);  // L == 8 labels always exist
    float x1 = anyc ? cmax : thres;
    float x2 = anyc ? (anyi ? fmaxf(imax, thres) : thres)
                    : ((nu > 0u) ? umax : NEGF);
    float coef = anyc ? 1.0f : 0.5f;
    float dd = x2 - x1 + 0.1f;
    float rank = ((dd > 0.0f) ? 2.0f : 1.0f) * sigm(10.0f * dd);
    partials[b] = coef * rank;
  }
}

__global__ void final_reduce(const float* __restrict__ partials,
                             float* __restrict__ out) {
  __shared__ float sh[4];
  const int tid = threadIdx.x;
  const int lane = tid & 63;
  const int wid = tid >> 6;
  float s = 0.0f;
  for (int i = tid; i < BB; i += 256) s += partials[i];
#pragma unroll
  for (int off = 32; off >= 1; off >>= 1) s += __shfl_xor(s, off, 64);
  if (lane == 0) sh[wid] = s;
  __syncthreads();
  if (tid == 0) out[0] = (sh[0] + sh[1] + sh[2] + sh[3]) * (1.0f / (float)BB);
}

extern "C" void kernel_launch(void* const* d_in, const int* in_sizes, int n_in,
                              void* d_out, int out_size, void* d_ws,
                              size_t ws_size, hipStream_t stream) {
  const float* x = (const float*)d_in[0];
  const float* y = (const float*)d_in[1];
  // d_in[2] (y_neg) is faithfully ignored — it never affects the loss.
  const unsigned char* wl = (const unsigned char*)d_in[3];
  float* out = (float*)d_out;
  unsigned* wsu = (unsigned*)d_ws;
  float* partials = (float*)((char*)d_ws + WS_PARTIALS_OFF);
  unsigned* counts = (unsigned*)((char*)d_ws + WS_COUNTS_OFF);
  unsigned* cand = (unsigned*)((char*)d_ws + WS_CAND_OFF);
  unsigned* hist = (unsigned*)((char*)d_ws + WS_CAND_OFF);  // pre-cand reuse

  hipMemsetAsync(d_ws, 0, 16, stream);                    // ctrl words
  hipMemsetAsync(counts, 0, BB * 4, stream);              // per-row counts
  hipMemsetAsync(hist, 0, 65536 * 4, stream);             // 16-bit histogram
  wl_sniff<<<64, 256, 0, stream>>>((const unsigned*)wl, wsu);
  wl_compact<<<(CC + 255) / 256, 256, 0, stream>>>(wl, wsu);
  hist16<<<256, 256, 0, stream>>>(x, hist);
  pick_tau16<<<1, 1024, 0, stream>>>(hist, wsu);
  stream_collect<<<2048, 256, 0, stream>>>(x, wsu, counts, cand);
  finalize<<<BB, 256, 0, stream>>>(x, y, wsu, counts, cand, partials);
  final_reduce<<<1, 256, 0, stream>>>(partials, out);
}

// Round 11
// 266.589 us; speedup vs baseline: 1.6251x; 1.6251x over previous
//
#include <hip/hip_runtime.h>

// Problem constants (from reference)
#define CC 9605
#define BB 2048
#define LL 8
#define CAND_MAX 384     // fallback candidate cap
#define ROWCAP 96        // per-row collected-candidate cap
#define NEGF (-1e30f)

// d_ws layout:
//   wsu[0] = wl entry count (atomic)   wsu[1] = dtype sniff flags
//   wsu[3] = tau (enc threshold, written by sample_tau)
//   wsu[4 .. 4+2048)   whitelist entries (col<<8 | mask)
//   byte 16384: float partials[2048]
//   byte 24576: unsigned counts[2048]
//   byte 32768: unsigned cand[2048*96]  (~786 KB)
#define WS_PARTIALS_OFF 16384
#define WS_COUNTS_OFF 24576
#define WS_CAND_OFF 32768

__device__ __forceinline__ unsigned enc_f(float f) {
  unsigned u = __float_as_uint(f);
  return (u & 0x80000000u) ? ~u : (u | 0x80000000u);
}
__device__ __forceinline__ float dec_u(unsigned e) {
  unsigned u = (e & 0x80000000u) ? (e & 0x7fffffffu) : ~e;
  return __uint_as_float(u);
}
__device__ __forceinline__ float sigm(float z) {
  return 1.0f / (1.0f + __expf(-z));
}

// ---- dtype sniff: byte signatures over the raw wl buffer ----
__global__ void wl_sniff(const unsigned* __restrict__ wlw,
                         unsigned* __restrict__ wsu) {
  const int nwords = (LL * CC) / 4;
  const int stride = gridDim.x * blockDim.x;
  unsigned f = 0u;
  for (int j = blockIdx.x * blockDim.x + threadIdx.x; j < nwords; j += stride) {
    unsigned w = wlw[j];
#pragma unroll
    for (int k = 0; k < 4; ++k) {
      unsigned b = (w >> (8 * k)) & 255u;
      if (b == 1u)    { f |= 2u; if (k != 0) f |= 1u; }
      if (b == 0x3fu) { f |= 8u; if (k == 1) f |= 4u; }
    }
  }
#pragma unroll
  for (int off = 32; off >= 1; off >>= 1) f |= __shfl_xor(f, off, 64);
  if ((threadIdx.x & 63) == 0 && f) atomicOr(&wsu[1], f);
}

__global__ void wl_compact(const unsigned char* __restrict__ wl,
                           unsigned* __restrict__ wsu) {
  const int tid = threadIdx.x;
  const int lane = tid & 63;
  const int c = blockIdx.x * 256 + tid;
  const unsigned g = wsu[1];
  const int dt = (g & 1u) ? 0 : (g & 4u) ? 3 : (g & 2u) ? 1 : (g & 8u) ? 2 : 0;
  const int* wl32 = (const int*)wl;
  const float* wlf = (const float*)wl;
  const unsigned short* wlh = (const unsigned short*)wl;
  unsigned m = 0u;
  if (c < CC) {
#pragma unroll
    for (int l = 0; l < LL; ++l) {
      int j = l * CC + c;
      bool on;
      if (dt == 0) on = (wl[j] != 0);
      else if (dt == 1) on = (wl32[j] != 0);
      else if (dt == 2) on = (wlf[j] != 0.0f);
      else on = (wlh[j] != 0);
      if (on) m |= (1u << l);
    }
  }
  unsigned long long bal = __ballot(m != 0u);
  if (bal) {
    unsigned wcnt = (unsigned)__popcll(bal);
    unsigned basep = 0u;
    if (lane == 0) basep = atomicAdd(&wsu[0], wcnt);
    basep = __shfl(basep, 0, 64);
    if (m) {
      unsigned pos = basep + (unsigned)__popcll(bal & ((1ull << lane) - 1ull));
      if (pos < 2048u) wsu[4 + pos] = ((unsigned)c << 8) | m;
    }
  }
}

// ---- sample_tau: ONE block, exact probe on row 0 -> tau with per-row
//      expected candidate count ~45-72. Correctness never depends on tau
//      (finalize has an exact fallback); tau only sets the fallback rate. ----
__global__ __launch_bounds__(256) void sample_tau(const float* __restrict__ x,
                                                  unsigned* __restrict__ wsu) {
  __shared__ __align__(16) unsigned sh_row[9608];  // 2402 uint4
  __shared__ unsigned sh_redM[4];
  __shared__ unsigned sh_redC[4];
  const int tid = threadIdx.x;
  const int lane = tid & 63;
  const int wid = tid >> 6;
  // row 0: base aligned, ngroups = 2401 (2401*4 = 9604), 1 tail elem
  const float4* xv = (const float4*)x;
  uint4* rv = (uint4*)sh_row;
  unsigned mx = 0u;
#pragma unroll
  for (int i = 0; i < 10; ++i) {
    int g = tid + (i << 8);
    if (g < 2401) {
      float4 v = xv[g];
      uint4 e;
      e.x = enc_f(v.x); e.y = enc_f(v.y); e.z = enc_f(v.z); e.w = enc_f(v.w);
      mx = max(mx, max(max(e.x, e.y), max(e.z, e.w)));
      rv[g] = e;
    }
  }
  if (tid == 0) {
    unsigned e = enc_f(x[9604]);
    sh_row[9604] = e;
  }
  if (tid < 3) sh_row[9605 + tid] = 0u;
#pragma unroll
  for (int off = 32; off >= 1; off >>= 1) mx = max(mx, __shfl_xor(mx, off, 64));
  if (lane == 0) sh_redM[wid] = mx;
  __syncthreads();
  unsigned Emax = max(max(sh_redM[0], sh_redM[1]), max(sh_redM[2], sh_redM[3]));
  // include the tail element (thread 0 wrote it after the max pass)
  Emax = max(Emax, sh_row[9604]);

  auto blk_count = [&](unsigned T) -> unsigned {
    unsigned cnt = 0u;
#pragma unroll
    for (int i = 0; i < 10; ++i) {
      int g = tid + (i << 8);
      if (g < 2402) {
        uint4 v = rv[g];
        cnt += (v.x >= T) + (v.y >= T) + (v.z >= T) + (v.w >= T);
      }
    }
#pragma unroll
    for (int off = 32; off >= 1; off >>= 1) cnt += __shfl_xor(cnt, off, 64);
    __syncthreads();
    if (lane == 0) sh_redC[wid] = cnt;
    __syncthreads();
    return sh_redC[0] + sh_redC[1] + sh_redC[2] + sh_redC[3];
  };

  const unsigned STEP = 1u << 22;
  unsigned lo = (Emax > STEP) ? (Emax - STEP) : 1u;
  unsigned hi = Emax + 1u;
  unsigned c = blk_count(lo);
  while (c < 45u && lo > 1u) {
    hi = lo;
    lo = (lo > STEP) ? (lo - STEP) : 1u;
    c = blk_count(lo);
  }
  // bisect until count(lo) in [45, 72] (or window collapse on mass ties)
  while (c > 72u && (hi - lo) > 1u) {
    unsigned mid = lo + ((hi - lo) >> 1);
    unsigned cm = blk_count(mid);
    if (cm >= 45u) { lo = mid; c = cm; } else { hi = mid; }
  }
  if (tid == 0) wsu[3] = lo;
}

// ---- stream_collect: pure coalesced stream of x; append enc>=tau per row ---
__global__ __launch_bounds__(256) void stream_collect(
    const float* __restrict__ x, const unsigned* __restrict__ wsu,
    unsigned* __restrict__ counts, unsigned* __restrict__ cand) {
  const unsigned tau = wsu[3];
  const int NG = (CC * BB) / 4;  // 4,917,760 exactly
  const int stride = gridDim.x * blockDim.x;
  const float4* xv = (const float4*)x;
  for (int g = blockIdx.x * blockDim.x + threadIdx.x; g < NG; g += stride) {
    float4 v = xv[g];
    unsigned idx = (unsigned)g << 2;
    unsigned r = idx / 9605u;          // compiler magic-mul
    unsigned rem = idx - r * 9605u;
    unsigned e0 = enc_f(v.x), e1 = enc_f(v.y);
    unsigned e2 = enc_f(v.z), e3 = enc_f(v.w);
    if (e0 >= tau) {
      unsigned s = atomicAdd(&counts[r], 1u);
      if (s < (unsigned)ROWCAP) cand[r * ROWCAP + s] = e0;
    }
    if (e1 >= tau) {
      unsigned rk = r + (rem + 1u >= 9605u);
      unsigned s = atomicAdd(&counts[rk], 1u);
      if (s < (unsigned)ROWCAP) cand[rk * ROWCAP + s] = e1;
    }
    if (e2 >= tau) {
      unsigned rk = r + (rem + 2u >= 9605u);
      unsigned s = atomicAdd(&counts[rk], 1u);
      if (s < (unsigned)ROWCAP) cand[rk * ROWCAP + s] = e2;
    }
    if (e3 >= tau) {
      unsigned rk = r + (rem + 3u >= 9605u);
      unsigned s = atomicAdd(&counts[rk], 1u);
      if (s < (unsigned)ROWCAP) cand[rk * ROWCAP + s] = e3;
    }
  }
}

// ---- finalize: per-row top-11 (from candidates, exact fallback if needed)
//      + whitelist gather + epilogue ----
__global__ __launch_bounds__(256) void finalize(
    const float* __restrict__ x, const float* __restrict__ y,
    const unsigned* __restrict__ wsu, const unsigned* __restrict__ counts,
    const unsigned* __restrict__ cand, float* __restrict__ partials) {
  __shared__ unsigned sh_cand[CAND_MAX];
  __shared__ unsigned sh_redM[4];
  __shared__ unsigned sh_redC[4];
  __shared__ unsigned sh_cnt;
  __shared__ unsigned sh_e11;
  __shared__ float sh_wl[4][10];

  const int tid = threadIdx.x;
  const int lane = tid & 63;
  const int wid = tid >> 6;
  const int b = blockIdx.x;
  const long long base = (long long)b * CC;

  // whitelist gather loads first (latency overlaps selection)
  const unsigned nu = wsu[0];
  const unsigned* ents = wsu + 4;
  const bool h0 = (unsigned)tid < nu;
  const bool h1 = (unsigned)(tid + 256) < nu;
  unsigned ent0 = 0u, ent1 = 0u;
  float gx0 = NEGF, gy0 = 0.0f, gx1 = NEGF, gy1 = 0.0f;
  if (h0) ent0 = ents[tid];
  if (h1) ent1 = ents[tid + 256];
  if (h0) { gx0 = x[base + (ent0 >> 8)]; gy0 = y[base + (ent0 >> 8)]; }
  if (h1) { gx1 = x[base + (ent1 >> 8)]; gy1 = y[base + (ent1 >> 8)]; }

  const unsigned cnt = counts[b];
  unsigned E11 = 0u;
  if (cnt >= 11u && cnt <= (unsigned)ROWCAP) {
    // ---- fast path: exact top-11 of collected candidates (wave 0) ----
    if (wid == 0) {
      const unsigned* gc = cand + (unsigned)b * ROWCAP;
      unsigned a0 = ((unsigned)lane < cnt) ? gc[lane] : 0u;
      unsigned a1 = ((unsigned)(lane + 64) < cnt) ? gc[lane + 64] : 0u;
      unsigned ans = 0u;
      for (int r = 0; r < 11; ++r) {
        unsigned lmx = max(a0, a1);
        unsigned wm = lmx;
#pragma unroll
        for (int off = 32; off >= 1; off >>= 1)
          wm = max(wm, __shfl_xor(wm, off, 64));
        ans = wm;
        if (r < 10) {
          unsigned long long bal = __ballot(lmx == wm);
          int first = (int)__ffsll((long long)bal) - 1;
          if (lane == first) {
            if (a0 == wm) a0 = 0u; else a1 = 0u;
          }
        }
      }
      if (lane == 0) sh_e11 = ans;
    }
    __syncthreads();
    E11 = sh_e11;
  } else {
    // ---- exact fallback: re-scan this row from global (L3-resident) ----
    if (tid == 0) sh_cnt = 0u;
    unsigned mx = 0u;
    for (int i = tid; i < CC; i += 256) mx = max(mx, enc_f(x[base + i]));
#pragma unroll
    for (int off = 32; off >= 1; off >>= 1)
      mx = max(mx, __shfl_xor(mx, off, 64));
    if (lane == 0) sh_redM[wid] = mx;
    __syncthreads();
    const unsigned Emax =
        max(max(sh_redM[0], sh_redM[1]), max(sh_redM[2], sh_redM[3]));

    auto gcount = [&](unsigned T) -> unsigned {
      unsigned c2 = 0u;
      for (int i = tid; i < CC; i += 256) c2 += (enc_f(x[base + i]) >= T);
#pragma unroll
      for (int off = 32; off >= 1; off >>= 1) c2 += __shfl_xor(c2, off, 64);
      __syncthreads();
      if (lane == 0) sh_redC[wid] = c2;
      __syncthreads();
      return sh_redC[0] + sh_redC[1] + sh_redC[2] + sh_redC[3];
    };

    const unsigned STEP = 1u << 22;
    bool done = false;
    unsigned lo = (Emax > STEP) ? (Emax - STEP) : 1u;
    unsigned hi = Emax + 1u;
    unsigned c = gcount(lo);
    while (c < 11u && lo > 1u) {
      hi = lo;
      lo = (lo > STEP) ? (lo - STEP) : 1u;
      c = gcount(lo);
    }
    while (c > CAND_MAX) {
      if (hi - lo <= 1u) { E11 = lo; done = true; break; }
      unsigned mid = lo + ((hi - lo) >> 1);
      unsigned cm = gcount(mid);
      if (cm >= 11u) { lo = mid; c = cm; } else { hi = mid; }
    }
    if (!done) {
      for (int i = tid; i < CC; i += 256) {
        unsigned e = enc_f(x[base + i]);
        bool pr = (e >= lo);
        unsigned long long bal = __ballot(pr);
        if (bal) {
          unsigned wcnt = (unsigned)__popcll(bal);
          unsigned basep = 0u;
          if (lane == 0) basep = atomicAdd(&sh_cnt, wcnt);
          basep = __shfl(basep, 0, 64);
          if (pr) {
            unsigned posn =
                basep + (unsigned)__popcll(bal & ((1ull << lane) - 1ull));
            sh_cand[posn] = e;
          }
        }
      }
      __syncthreads();
      if (wid == 0) {
        unsigned v0[6];
#pragma unroll
        for (int j = 0; j < 6; ++j) {
          unsigned idx = (unsigned)lane + 64u * j;
          v0[j] = (idx < c) ? sh_cand[idx] : 0u;
        }
        unsigned ans = 0u;
        for (int r = 0; r < 11; ++r) {
          unsigned lmx = v0[0];
#pragma unroll
          for (int j = 1; j < 6; ++j) lmx = max(lmx, v0[j]);
          unsigned wm = lmx;
#pragma unroll
          for (int off = 32; off >= 1; off >>= 1)
            wm = max(wm, __shfl_xor(wm, off, 64));
          ans = wm;
          if (r < 10) {
            unsigned long long bal = __ballot(lmx == wm);
            int first = (int)__ffsll((long long)bal) - 1;
            if (lane == first) {
              bool rm = false;
#pragma unroll
              for (int j = 0; j < 6; ++j)
                if (!rm && v0[j] == wm) { v0[j] = 0u; rm = true; }
            }
          }
        }
        if (lane == 0) sh_e11 = ans;
      }
      __syncthreads();
      E11 = sh_e11;
    }
  }

  // ---- whitelist gather reduce ----
  float lm[8];
#pragma unroll
  for (int l = 0; l < 8; ++l) lm[l] = NEGF;
  unsigned pmask = 0u;  // bits0-7: present; bits8-15: has positive
  if (h0) {
    unsigned mk = ent0 & 255u;
    pmask |= mk;
    if (gy0 > 0.0f) pmask |= (mk << 8);
#pragma unroll
    for (int l = 0; l < 8; ++l)
      if ((mk >> l) & 1u) lm[l] = fmaxf(lm[l], gx0);
  }
  if (h1) {
    unsigned mk = ent1 & 255u;
    pmask |= mk;
    if (gy1 > 0.0f) pmask |= (mk << 8);
#pragma unroll
    for (int l = 0; l < 8; ++l)
      if ((mk >> l) & 1u) lm[l] = fmaxf(lm[l], gx1);
  }
  for (unsigned e = (unsigned)tid + 512u; e < nu; e += 256u) {  // safety net
    unsigned ent = ents[e];
    unsigned mk = ent & 255u;
    float xv = x[base + (ent >> 8)];
    float yv = y[base + (ent >> 8)];
    pmask |= mk;
    if (yv > 0.0f) pmask |= (mk << 8);
#pragma unroll
    for (int l = 0; l < 8; ++l)
      if ((mk >> l) & 1u) lm[l] = fmaxf(lm[l], xv);
  }
#pragma unroll
  for (int off = 32; off >= 1; off >>= 1) {
    pmask |= __shfl_xor(pmask, off, 64);
#pragma unroll
    for (int l = 0; l < 8; ++l) lm[l] = fmaxf(lm[l], __shfl_xor(lm[l], off, 64));
  }
  if (lane == 0) {
#pragma unroll
    for (int l = 0; l < 8; ++l) sh_wl[wid][l] = lm[l];
    sh_wl[wid][8] = __uint_as_float(pmask);
  }
  __syncthreads();

  // ---- epilogue ----
  if (tid == 0) {
    float LM[8];
    unsigned PM = 0u;
#pragma unroll
    for (int l = 0; l < 8; ++l) LM[l] = NEGF;
    for (int w = 0; w < 4; ++w) {
#pragma unroll
      for (int l = 0; l < 8; ++l) LM[l] = fmaxf(LM[l], sh_wl[w][l]);
      PM |= __float_as_uint(sh_wl[w][8]);
    }
    unsigned PR = PM & 255u, PO = (PM >> 8) & 255u;
    float thres = fmaxf(sigm(dec_u(E11)), 0.5f);
    float cmax = NEGF, imax = NEGF, umax = NEGF;
#pragma unroll
    for (int l = 0; l < 8; ++l) {
      if ((PR >> l) & 1u) {
        float ml = sigm(LM[l]);
        umax = fmaxf(umax, ml);
        if ((PO >> l) & 1u) cmax = fmaxf(cmax, ml);
        else imax = fmaxf(imax, ml);
      }
    }
    bool anyc = (PO != 0u);
    bool anyi = (PO != 255u);  // L == 8 labels always exist
    float x1 = anyc ? cmax : thres;
    float x2 = anyc ? (anyi ? fmaxf(imax, thres) : thres)
                    : ((nu > 0u) ? umax : NEGF);
    float coef = anyc ? 1.0f : 0.5f;
    float dd = x2 - x1 + 0.1f;
    float rank = ((dd > 0.0f) ? 2.0f : 1.0f) * sigm(10.0f * dd);
    partials[b] = coef * rank;
  }
}

__global__ void final_reduce(const float* __restrict__ partials,
                             float* __restrict__ out) {
  __shared__ float sh[4];
  const int tid = threadIdx.x;
  const int lane = tid & 63;
  const int wid = tid >> 6;
  float s = 0.0f;
  for (int i = tid; i < BB; i += 256) s += partials[i];
#pragma unroll
  for (int off = 32; off >= 1; off >>= 1) s += __shfl_xor(s, off, 64);
  if (lane == 0) sh[wid] = s;
  __syncthreads();
  if (tid == 0) out[0] = (sh[0] + sh[1] + sh[2] + sh[3]) * (1.0f / (float)BB);
}

extern "C" void kernel_launch(void* const* d_in, const int* in_sizes, int n_in,
                              void* d_out, int out_size, void* d_ws,
                              size_t ws_size, hipStream_t stream) {
  const float* x = (const float*)d_in[0];
  const float* y = (const float*)d_in[1];
  // d_in[2] (y_neg) is faithfully ignored — it never affects the loss.
  const unsigned char* wl = (const unsigned char*)d_in[3];
  float* out = (float*)d_out;
  unsigned* wsu = (unsigned*)d_ws;
  float* partials = (float*)((char*)d_ws + WS_PARTIALS_OFF);
  unsigned* counts = (unsigned*)((char*)d_ws + WS_COUNTS_OFF);
  unsigned* cand = (unsigned*)((char*)d_ws + WS_CAND_OFF);

  hipMemsetAsync(d_ws, 0, 16, stream);        // ctrl words
  hipMemsetAsync(counts, 0, BB * 4, stream);  // per-row counts
  wl_sniff<<<64, 256, 0, stream>>>((const unsigned*)wl, wsu);
  wl_compact<<<(CC + 255) / 256, 256, 0, stream>>>(wl, wsu);
  sample_tau<<<1, 256, 0, stream>>>(x, wsu);
  stream_collect<<<2048, 256, 0, stream>>>(x, wsu, counts, cand);
  finalize<<<BB, 256, 0, stream>>>(x, y, wsu, counts, cand, partials);
  final_reduce<<<1, 256, 0, stream>>>(partials, out);
}